// Round 13
// baseline (67.692 us; speedup 1.0000x reference)
//
#include <hip/hip_runtime.h>
#include <hip/hip_bf16.h>

#define B_DIM 4096
#define I_DIM 2048
#define H_DIM 2048

typedef unsigned char u8;
typedef unsigned short u16;
typedef unsigned int u32;
typedef __attribute__((ext_vector_type(4))) float f32x4;
typedef __attribute__((ext_vector_type(4))) int i32x4;
typedef __attribute__((ext_vector_type(8))) int i32x8;

#define SBAR __builtin_amdgcn_sched_barrier(0)

__device__ __forceinline__ void gload_lds16(const void* g, void* l) {
  __builtin_amdgcn_global_load_lds(
      (const __attribute__((address_space(1))) void*)g,
      (__attribute__((address_space(3))) void*)l, 16, 0, 0);
}

// branchless fp4 (e2m1) encoder: quantizes v*inv_scale to e2m1 code
__device__ __forceinline__ u32 f2fp4(float v, float inv_scale) {
  const float a = fabsf(v) * inv_scale;
  u32 m = (u32)(a > 0.25f) + (u32)(a > 0.75f) + (u32)(a > 1.25f) +
          (u32)(a > 1.75f) + (u32)(a > 2.5f) + (u32)(a > 3.5f) + (u32)(a > 5.0f);
  return ((__float_as_uint(v) >> 31) << 3) | m;
}

// ---------------------------------------------------------------------------
// Kernel A (fused prep):
//  blocks [0, 4096):    coeff [I,H] fp32 -> coeffT fp4 x8 (HW 2^-3) ct4[H,I/2]
//  blocks [4096, 5120): x -> fp4 xf4[B,I/2]; (an,bn) -> fp4-pair ab4[I,H]
// ---------------------------------------------------------------------------
__global__ void prep_all(const float* __restrict__ x, const float* __restrict__ coeff,
                         const float* __restrict__ an, const float* __restrict__ bn,
                         u16* __restrict__ xf4, u16* __restrict__ ct4,
                         u32* __restrict__ ab4) {
  if (blockIdx.x < 4096) {
    __shared__ float tile[32][33];
    const int h0 = (blockIdx.x & 63) * 32;
    const int i0 = (blockIdx.x >> 6) * 32;
    const int tid = threadIdx.x;
    const int tx = tid & 31;
    const int ty = tid >> 5;
    for (int r = ty; r < 32; r += 8)
      tile[r][tx] = coeff[(long)(i0 + r) * H_DIM + (h0 + tx)];
    __syncthreads();
    const int hl = tid >> 3;
    const int q = (tid & 7) * 4;
    u32 w = f2fp4(tile[q + 0][hl], 8.f) | (f2fp4(tile[q + 1][hl], 8.f) << 4) |
            (f2fp4(tile[q + 2][hl], 8.f) << 8) | (f2fp4(tile[q + 3][hl], 8.f) << 12);
    ct4[(long)(h0 + hl) * (I_DIM / 4) + ((i0 + q) >> 2)] = (u16)w;
    return;
  }
  const long NX4 = (long)B_DIM * I_DIM / 4;
  const long NA4 = (long)I_DIM * H_DIM / 4;
  const long total = NX4 + NA4;
  const long stride = (long)1024 * blockDim.x;
  for (long t = (long)(blockIdx.x - 4096) * blockDim.x + threadIdx.x; t < total;
       t += stride) {
    if (t < NX4) {
      float4 v = *(const float4*)(x + t * 4);
      u32 b0 = f2fp4(v.x, 1.f) | (f2fp4(v.y, 1.f) << 4);
      u32 b1 = f2fp4(v.z, 1.f) | (f2fp4(v.w, 1.f) << 4);
      xf4[t] = (u16)(b0 | (b1 << 8));
    } else {
      long p = (t - NX4) * 4;
      float4 va = *(const float4*)(an + p);
      float4 vb = *(const float4*)(bn + p);
      u32 b0 = f2fp4(va.x, 8.f) | (f2fp4(vb.x, 8.f) << 4);
      u32 b1 = f2fp4(va.y, 8.f) | (f2fp4(vb.y, 8.f) << 4);
      u32 b2 = f2fp4(va.z, 8.f) | (f2fp4(vb.z, 8.f) << 4);
      u32 b3 = f2fp4(va.w, 8.f) | (f2fp4(vb.w, 8.f) << 4);
      ab4[p >> 2] = b0 | (b1 << 8) | (b2 << 16) | (b3 << 24);
    }
  }
}

// ---------------------------------------------------------------------------
// fp4 GEMM, m201-style 4-phase interleave. BM=128, BN=256, K-step 128 B.
// 8 waves (2M x 4N), per-wave 64x64 (4x4 frags of 16x16x128).
// Triple-buffered LDS (3 x 48 KB), depth-2 prefetch spread across phases,
// counted vmcnt(6) once per K-tile, XOR-swizzled LDS, setprio MFMA clusters.
// Per buffer: A (128r x 128B) @ 0, B (256r x 128B) @ 16384.
// ---------------------------------------------------------------------------
#define NBUF 49152

__device__ __forceinline__ void stageA1(const char* Ab, long kbyte, long lda,
                                        char* buf, int tid, int i) {
  const int o = i * 8192 + tid * 16;
  const int row = o >> 7;
  const int ls = ((((o >> 4) & 7) ^ (row & 7)) << 4);
  gload_lds16(Ab + (long)row * lda + kbyte + ls, buf + o);
}
__device__ __forceinline__ void stageB1(const char* Bb, long kbyte, long ldb,
                                        char* buf, int tid, int i) {
  const int o = i * 8192 + tid * 16;
  const int row = o >> 7;
  const int ls = ((((o >> 4) & 7) ^ (row & 7)) << 4);
  gload_lds16(Bb + (long)row * ldb + kbyte + ls, buf + 16384 + o);
}

__device__ __forceinline__ i32x4 frag_ld16(const char* S, int row, int slot) {
  return *(const i32x4*)(S + row * 128 + ((slot ^ (row & 7)) << 4));
}

template <int SA, int SB>
__device__ __forceinline__ void gemm_kloop_fp4(const char* __restrict__ A,
                                               const char* __restrict__ Bt,
                                               int rowA0, int colB0, long Kbytes,
                                               char* smem, f32x4 acc[4][4]) {
  const int tid = threadIdx.x;
  const int lane = tid & 63;
  const int wid = tid >> 6;   // 0..7
  const int wr = wid >> 2;    // 0..1 (M)
  const int wc = wid & 3;     // 0..3 (N)
  const long lda = Kbytes, ldb = Kbytes;
  const char* Ab = A + (long)rowA0 * lda;
  const char* Bb = Bt + (long)colB0 * ldb;
  const int arow = wr * 64 + (lane & 15);
  const int brow = wc * 64 + (lane & 15);
  const int g = lane >> 4;    // 0..3
  const int nt = (int)(Kbytes >> 7);

  char* b0 = smem;             // tile t (read)
  char* b1 = smem + NBUF;      // tile t+1 (landing)
  char* b2 = smem + 2 * NBUF;  // tile t+2 (stage target = old t-1)

  // prologue: tiles 0 and 1 (6 loads each)
#pragma unroll
  for (int i = 0; i < 2; ++i) stageA1(Ab, 0, lda, b0, tid, i);
#pragma unroll
  for (int i = 0; i < 4; ++i) stageB1(Bb, 0, ldb, b0, tid, i);
#pragma unroll
  for (int i = 0; i < 2; ++i) stageA1(Ab, 128, lda, b1, tid, i);
#pragma unroll
  for (int i = 0; i < 4; ++i) stageB1(Bb, 128, ldb, b1, tid, i);

  for (int t = 0; t < nt; ++t) {
    if (t < nt - 1) asm volatile("s_waitcnt vmcnt(6)" ::: "memory");
    else            asm volatile("s_waitcnt vmcnt(0)" ::: "memory");
    SBAR;
    __builtin_amdgcn_s_barrier();
    SBAR;

    const bool st = (t + 2 < nt);
    const long kb2 = (long)(t + 2) * 128;
    i32x8 af[2][4], bfr[2][4];  // low i32x4 holds the fp4 operand

    // ---- P0: read af[s0][0..3] + bfr[s0][0..1]; stage A0,A1; MFMA s0 x n01
#pragma unroll
    for (int m = 0; m < 4; ++m)
      *(i32x4*)&af[0][m] = frag_ld16(b0, arow + m * 16, g);
    *(i32x4*)&bfr[0][0] = frag_ld16(b0 + 16384, brow, g);
    *(i32x4*)&bfr[0][1] = frag_ld16(b0 + 16384, brow + 16, g);
    if (st) { stageA1(Ab, kb2, lda, b2, tid, 0); stageA1(Ab, kb2, lda, b2, tid, 1); }
    SBAR;
    asm volatile("s_waitcnt lgkmcnt(0)" ::: "memory");
    SBAR;
    __builtin_amdgcn_s_setprio(1);
#pragma unroll
    for (int m = 0; m < 4; ++m)
#pragma unroll
      for (int n = 0; n < 2; ++n)
        acc[m][n] = __builtin_amdgcn_mfma_scale_f32_16x16x128_f8f6f4(
            af[0][m], bfr[0][n], acc[m][n], 4, 4, 0, SA, 0, SB);
    __builtin_amdgcn_s_setprio(0);
    SBAR;
    __builtin_amdgcn_s_barrier();

    // ---- P1: read af[s1][0..3] + bfr[s0][2..3]; stage B0,B1; MFMA s0 x n23
#pragma unroll
    for (int m = 0; m < 4; ++m)
      *(i32x4*)&af[1][m] = frag_ld16(b0, arow + m * 16, 4 + g);
    *(i32x4*)&bfr[0][2] = frag_ld16(b0 + 16384, brow + 32, g);
    *(i32x4*)&bfr[0][3] = frag_ld16(b0 + 16384, brow + 48, g);
    if (st) { stageB1(Bb, kb2, ldb, b2, tid, 0); stageB1(Bb, kb2, ldb, b2, tid, 1); }
    SBAR;
    asm volatile("s_waitcnt lgkmcnt(0)" ::: "memory");
    SBAR;
    __builtin_amdgcn_s_setprio(1);
#pragma unroll
    for (int m = 0; m < 4; ++m)
#pragma unroll
      for (int n = 2; n < 4; ++n)
        acc[m][n] = __builtin_amdgcn_mfma_scale_f32_16x16x128_f8f6f4(
            af[0][m], bfr[0][n], acc[m][n], 4, 4, 0, SA, 0, SB);
    __builtin_amdgcn_s_setprio(0);
    SBAR;
    __builtin_amdgcn_s_barrier();

    // ---- P2: read bfr[s1][0..1]; stage B2; MFMA s1 x n01
    *(i32x4*)&bfr[1][0] = frag_ld16(b0 + 16384, brow, 4 + g);
    *(i32x4*)&bfr[1][1] = frag_ld16(b0 + 16384, brow + 16, 4 + g);
    if (st) stageB1(Bb, kb2, ldb, b2, tid, 2);
    SBAR;
    asm volatile("s_waitcnt lgkmcnt(0)" ::: "memory");
    SBAR;
    __builtin_amdgcn_s_setprio(1);
#pragma unroll
    for (int m = 0; m < 4; ++m)
#pragma unroll
      for (int n = 0; n < 2; ++n)
        acc[m][n] = __builtin_amdgcn_mfma_scale_f32_16x16x128_f8f6f4(
            af[1][m], bfr[1][n], acc[m][n], 4, 4, 0, SA, 0, SB);
    __builtin_amdgcn_s_setprio(0);
    SBAR;
    __builtin_amdgcn_s_barrier();

    // ---- P3: read bfr[s1][2..3]; stage B3; MFMA s1 x n23
    *(i32x4*)&bfr[1][2] = frag_ld16(b0 + 16384, brow + 32, 4 + g);
    *(i32x4*)&bfr[1][3] = frag_ld16(b0 + 16384, brow + 48, 4 + g);
    if (st) stageB1(Bb, kb2, ldb, b2, tid, 3);
    SBAR;
    asm volatile("s_waitcnt lgkmcnt(0)" ::: "memory");
    SBAR;
    __builtin_amdgcn_s_setprio(1);
#pragma unroll
    for (int m = 0; m < 4; ++m)
#pragma unroll
      for (int n = 2; n < 4; ++n)
        acc[m][n] = __builtin_amdgcn_mfma_scale_f32_16x16x128_f8f6f4(
            af[1][m], bfr[1][n], acc[m][n], 4, 4, 0, SA, 0, SB);
    __builtin_amdgcn_s_setprio(0);
    SBAR;

    char* tmp = b0; b0 = b1; b1 = b2; b2 = tmp;
  }
}

// Square-ish XCD chunking: 256 blocks over 32(by) x 8(bx); each XCD owns an
// 8(by) x 4(bx) chunk -> per-XCD working set = 2+2 MB, fits the 4 MB L2.
__device__ __forceinline__ void tile_xy(int& bx, int& by) {
  const int bid = blockIdx.x;   // 0..255, 256 % 8 == 0
  const int xcd = bid & 7;
  const int loc = bid >> 3;     // 0..31
  bx = (xcd & 1) * 4 + (loc & 3);    // 0..7
  by = (xcd >> 1) * 8 + (loc >> 2);  // 0..31
}

// ---------------------------------------------------------------------------
// Kernel C: GEMM1 (MX-fp4)  phase = x @ coeff ; epilogue -> fp4 (cos|sin<<4)
// A scale 2^0 (0x7F), B scale 2^-3 (0x7C)
// ---------------------------------------------------------------------------
__global__ __launch_bounds__(512, 1) void gemm_phase(const char* __restrict__ xf4,
                                                     const char* __restrict__ ct4,
                                                     u8* __restrict__ cs4) {
  __shared__ __align__(16) char smem[3 * NBUF];
  int bx, by;
  tile_xy(bx, by);
  const int rowA0 = by * 128;
  const int colB0 = bx * 256;
  f32x4 acc[4][4];
#pragma unroll
  for (int m = 0; m < 4; ++m)
#pragma unroll
    for (int n = 0; n < 4; ++n)
#pragma unroll
      for (int j = 0; j < 4; ++j) acc[m][n][j] = 0.0f;

  gemm_kloop_fp4<0x7F7F7F7F, 0x7C7C7C7C>(xf4, ct4, rowA0, colB0, I_DIM / 2, smem, acc);

  const int lane = threadIdx.x & 63;
  const int wid = threadIdx.x >> 6;
  const int wr = wid >> 2, wc = wid & 3;
#pragma unroll
  for (int m = 0; m < 4; ++m) {
#pragma unroll
    for (int n = 0; n < 4; ++n) {
      const int col = colB0 + wc * 64 + n * 16 + (lane & 15);
#pragma unroll
      for (int j = 0; j < 4; ++j) {
        const int row = rowA0 + wr * 64 + m * 16 + (lane >> 4) * 4 + j;
        const float p = acc[m][n][j];
        const u32 b = f2fp4(__cosf(p), 4.f) | (f2fp4(__sinf(p), 4.f) << 4);
        cs4[(long)row * H_DIM + col] = (u8)b;
      }
    }
  }
}

// ---------------------------------------------------------------------------
// Kernel D: GEMM2 (MX-fp4)  gain = cs4 @ ab4^T + H*bias
// A scale 2^-2 (0x7D), B scale 2^-3 (0x7C)
// ---------------------------------------------------------------------------
__global__ __launch_bounds__(512, 1) void gemm_gain(const char* __restrict__ cs4,
                                                    const char* __restrict__ ab4,
                                                    const float* __restrict__ bias,
                                                    float* __restrict__ out) {
  __shared__ __align__(16) char smem[3 * NBUF];
  int bx, by;
  tile_xy(bx, by);
  const int rowA0 = by * 128;
  const int colB0 = bx * 256;
  f32x4 acc[4][4];
#pragma unroll
  for (int m = 0; m < 4; ++m)
#pragma unroll
    for (int n = 0; n < 4; ++n)
#pragma unroll
      for (int j = 0; j < 4; ++j) acc[m][n][j] = 0.0f;

  gemm_kloop_fp4<0x7D7D7D7D, 0x7C7C7C7C>(cs4, ab4, rowA0, colB0, H_DIM, smem, acc);

  const int lane = threadIdx.x & 63;
  const int wid = threadIdx.x >> 6;
  const int wr = wid >> 2, wc = wid & 3;
#pragma unroll
  for (int m = 0; m < 4; ++m) {
#pragma unroll
    for (int n = 0; n < 4; ++n) {
      const int col = colB0 + wc * 64 + n * 16 + (lane & 15);
      const float bv = 2048.0f * bias[col];
#pragma unroll
      for (int j = 0; j < 4; ++j) {
        const int row = rowA0 + wr * 64 + m * 16 + (lane >> 4) * 4 + j;
        out[(long)row * I_DIM + col] = acc[m][n][j] + bv;
      }
    }
  }
}

// ---------------------------------------------------------------------------
extern "C" void kernel_launch(void* const* d_in, const int* in_sizes, int n_in,
                              void* d_out, int out_size, void* d_ws, size_t ws_size,
                              hipStream_t stream) {
  const float* x     = (const float*)d_in[0];
  const float* coeff = (const float*)d_in[1];
  const float* an    = (const float*)d_in[2];
  const float* bn    = (const float*)d_in[3];
  const float* bias  = (const float*)d_in[4];
  float* out = (float*)d_out;

  char* ws = (char*)d_ws;
  char* xf4 = ws;                        //  4 MB  [B, I/2] fp4 (x, scale 1)
  char* ct4 = ws + (4L << 20);           //  2 MB  [H, I/2] fp4 (coeff^T x8)
  char* ab4 = ws + (8L << 20);           //  4 MB  [I, H]   fp4-pair (an|bn<<4)
  u8*  cs4  = (u8*)(ws + (12L << 20));   //  8 MB  [B, H]   fp4-pair (cos|sin<<4)

  prep_all<<<5120, 256, 0, stream>>>(x, coeff, an, bn, (u16*)xf4, (u16*)ct4,
                                     (u32*)ab4);
  gemm_phase<<<256, 512, 0, stream>>>(xf4, ct4, cs4);
  gemm_gain<<<256, 512, 0, stream>>>((const char*)cs4, (const char*)ab4, bias, out);
}